// Round 3
// baseline (168.852 us; speedup 1.0000x reference)
//
#include <hip/hip_runtime.h>

// =============================================================================
// QuantumContrastiveModel — mathematical reduction:
//   StronglyEntanglingLayers is a fixed 16x16 UNITARY applied to BOTH states;
//   fidelity |<U va|U vb>|^2 = (va.vb)^2 — the circuit cancels, theta unused.
//   With u = tanh(relu(x@W1+b1)@W2+b2):
//     fid = clip( (ua.ub)^2 / (max(|ua|,1e-8)*max(|ub|,1e-8))^2, 0, 1 )
//   R1: 170us latency-bound. R2: depth-1 prefetch -> 117us.
//   R3 (135us) / R4 (118us): occupancy 38->67%, W off the VMEM path — both
//       NO-OPs on profiled duration. Invariant across all: A-loads read 128B
//       column-chunks strided 3136B -> ~131K concurrent streams -> random-128B
//       DRAM behavior, ~1.9 TB/s HBM ceiling. Occupancy/requests irrelevant.
//   R5: make A-addresses SEQUENTIAL. 1 wave/block, 8 pairs: stage 8 a-rows +
//       8 b-rows as lane-contiguous 1KB loads walking whole rows (two ~25KB
//       sequential bursts per wave), cvt to bf16, transpose via LDS (stride
//       1616B = conflict-free fragment reads). K-loop reads A from LDS; W
//       keeps verified L2-resident fragment loads with depth-1 prefetch.
// =============================================================================

#define KDIM   784
#define HDIM   64
#define KSTEPS 25                        // ceil(784/32); last step zero-padded
#define W1S_ELEMS (KSTEPS * 4 * 64 * 8)  // 51200 bf16 in B-fragment order
#define W1S_BYTES (W1S_ELEMS * 2)        // 102400 bytes

#define LROW   808                       // bf16 row stride (1616B): m=0..7 hit
                                         // all 32 banks on ds_read_b128 -> free
#define NPAIR  8                         // pairs per wave(=block)

typedef float  f32x4  __attribute__((ext_vector_type(4)));
typedef short  bf16x8 __attribute__((ext_vector_type(8)));

__device__ __forceinline__ unsigned short f2bf(float f) {
  unsigned u = __float_as_uint(f);
  u += 0x7fffu + ((u >> 16) & 1u);       // round-to-nearest-even
  return (unsigned short)(u >> 16);
}

__device__ __forceinline__ float bf2f(unsigned short h) {
  return __uint_as_float(((unsigned)h) << 16);
}

__device__ __forceinline__ uint2 pack4(f32x4 v) {
  uint2 r;
  r.x = (unsigned)f2bf(v[0]) | ((unsigned)f2bf(v[1]) << 16);
  r.y = (unsigned)f2bf(v[2]) | ((unsigned)f2bf(v[3]) << 16);
  return r;
}

__device__ __forceinline__ float tanh_fast(float x) {
  float e = __expf(2.0f * x);
  return 1.0f - 2.0f / (e + 1.0f);       // exact limits at +-inf
}

// --- prep: W1 (784x64 f32) -> bf16 in MFMA B-fragment order, K padded to 800;
//           W2 (64x16) -> transposed (16x64) f32.  (unchanged, verified)
__global__ __launch_bounds__(256)
void prep_kernel(const float* __restrict__ W1, const float* __restrict__ W2,
                 unsigned short* __restrict__ w1s, float* __restrict__ w2t) {
  int tid = blockIdx.x * 256 + threadIdx.x;
  if (tid < W1S_ELEMS) {
    int j  = tid & 7;            // element within 8-wide fragment
    int l  = (tid >> 3) & 63;    // lane
    int st = tid >> 9;           // s*4 + t
    int s  = st >> 2;
    int t  = st & 3;
    int k  = s * 32 + (l >> 4) * 8 + j;   // B[k][n]: k = quad*8+j
    int n  = t * 16 + (l & 15);           //          n = lane&15
    float v = (k < KDIM) ? W1[k * HDIM + n] : 0.0f;
    w1s[tid] = f2bf(v);
  }
  if (tid < HDIM * 16) {
    int c = tid >> 6;            // 0..15
    int k = tid & 63;            // 0..63
    w2t[c * HDIM + k] = W2[k * 16 + c];
  }
}

// --- main: 1 wave / 64 threads / 8 pairs per block; grid = 8192.
//     A-frag rows 0-7 = a-pairs, 8-15 = b-pairs (one MFMA does both, verified R3).
__global__ __launch_bounds__(64)
void qcm_kernel(const float* __restrict__ img_a, const float* __restrict__ img_b,
                const float* __restrict__ b1,    const float* __restrict__ b2,
                const unsigned short* __restrict__ w1s,
                const float* __restrict__ w2t,
                float* __restrict__ out) {
  __shared__ __attribute__((aligned(16))) unsigned short L[16][LROW]; // 25856B

  const int lane = threadIdx.x;   // one wave per block
  const int m    = lane & 15;     // A-frag row / C-frag col
  const int quad = lane >> 4;
  const int p0   = blockIdx.x * NPAIR;

  // ---- stage: whole rows, lane-contiguous 1KB bursts, cvt->bf16, into LDS
  {
    const float* aB = img_a + (size_t)p0 * KDIM;
    const float* bB = img_b + (size_t)p0 * KDIM;
    #pragma unroll
    for (int r = 0; r < NPAIR; ++r) {
      const float* ra = aB + r * KDIM;
      const float* rb = bB + r * KDIM;
      f32x4 a0 = *(const f32x4*)(ra + lane * 4);
      f32x4 a1 = *(const f32x4*)(ra + 256 + lane * 4);
      f32x4 a2 = *(const f32x4*)(ra + 512 + lane * 4);
      f32x4 c0 = *(const f32x4*)(rb + lane * 4);
      f32x4 c1 = *(const f32x4*)(rb + 256 + lane * 4);
      f32x4 c2 = *(const f32x4*)(rb + 512 + lane * 4);
      *(uint2*)&L[r][lane * 4]           = pack4(a0);
      *(uint2*)&L[r][256 + lane * 4]     = pack4(a1);
      *(uint2*)&L[r][512 + lane * 4]     = pack4(a2);
      *(uint2*)&L[8 + r][lane * 4]       = pack4(c0);
      *(uint2*)&L[8 + r][256 + lane * 4] = pack4(c1);
      *(uint2*)&L[8 + r][512 + lane * 4] = pack4(c2);
      if (lane < 4) {                    // row tail: floats 768..784
        f32x4 ta = *(const f32x4*)(ra + 768 + lane * 4);
        f32x4 tb = *(const f32x4*)(rb + 768 + lane * 4);
        *(uint2*)&L[r][768 + lane * 4]     = pack4(ta);
        *(uint2*)&L[8 + r][768 + lane * 4] = pack4(tb);
      }
    }
    // zero K-pad cols 784..800 (read by tail K-step, quads 2,3)
    uint2 z; z.x = 0u; z.y = 0u;
    *(uint2*)&L[lane >> 2][784 + (lane & 3) * 4] = z;
  }
  __syncthreads();

  // ---- K-loop: A-frags from LDS, W-frags from L2 (depth-1 prefetch on both)
  f32x4 acc[4];
  #pragma unroll
  for (int t = 0; t < 4; ++t)
    acc[t][0] = acc[t][1] = acc[t][2] = acc[t][3] = 0.0f;

  const int4* bwl = (const int4*)w1s + lane;
  int4 w0 = bwl[0];
  int4 w1 = bwl[64];
  int4 w2 = bwl[128];
  int4 w3 = bwl[192];
  bf16x8 acur = *(const bf16x8*)&L[m][quad * 8];

  for (int s = 0; s < KSTEPS; ++s) {
    const int sp = (s + 1 < KSTEPS) ? s + 1 : s;   // tail: redundant reload
    int4 nw0 = bwl[sp * 256];
    int4 nw1 = bwl[sp * 256 + 64];
    int4 nw2 = bwl[sp * 256 + 128];
    int4 nw3 = bwl[sp * 256 + 192];
    bf16x8 anxt = *(const bf16x8*)&L[m][sp * 32 + quad * 8];

    acc[0] = __builtin_amdgcn_mfma_f32_16x16x32_bf16(
        acur, __builtin_bit_cast(bf16x8, w0), acc[0], 0, 0, 0);
    acc[1] = __builtin_amdgcn_mfma_f32_16x16x32_bf16(
        acur, __builtin_bit_cast(bf16x8, w1), acc[1], 0, 0, 0);
    acc[2] = __builtin_amdgcn_mfma_f32_16x16x32_bf16(
        acur, __builtin_bit_cast(bf16x8, w2), acc[2], 0, 0, 0);
    acc[3] = __builtin_amdgcn_mfma_f32_16x16x32_bf16(
        acur, __builtin_bit_cast(bf16x8, w3), acc[3], 0, 0, 0);

    w0 = nw0; w1 = nw1; w2 = nw2; w3 = nw3;
    acur = anxt;
  }
  __syncthreads();

  // ---- epilogue: bias + relu, park h as bf16 (C-frag: row=quad*4+j, col=t*16+m)
  unsigned short (*H)[72] = (unsigned short(*)[72])L;   // reuse LDS
  #pragma unroll
  for (int t = 0; t < 4; ++t) {
    float bias = b1[t * 16 + m];
    #pragma unroll
    for (int j = 0; j < 4; ++j) {
      float h = fmaxf(acc[t][j] + bias, 0.0f);
      H[quad * 4 + j][t * 16 + m] = f2bf(h);     // rows 0-7 a, 8-15 b
    }
  }
  __syncthreads();

  // ---- phase 2: 8 threads/pair; each computes 2 of 16 z-cols for a and b
  const int p = lane >> 3;           // 0..7 local pair
  const int q = lane & 7;            // cols q*2, q*2+1
  const unsigned short* ha_row = &H[p][0];
  const unsigned short* hb_row = &H[8 + p][0];

  float za[2], zb[2];
  za[0] = b2[q * 2];     zb[0] = za[0];
  za[1] = b2[q * 2 + 1]; zb[1] = za[1];

  for (int k = 0; k < HDIM; k += 4) {
    uint2 ua = *(const uint2*)(ha_row + k);
    uint2 ub = *(const uint2*)(hb_row + k);
    float a0 = bf2f((unsigned short)(ua.x & 0xffff));
    float a1 = bf2f((unsigned short)(ua.x >> 16));
    float a2 = bf2f((unsigned short)(ua.y & 0xffff));
    float a3 = bf2f((unsigned short)(ua.y >> 16));
    float b0v = bf2f((unsigned short)(ub.x & 0xffff));
    float b1v = bf2f((unsigned short)(ub.x >> 16));
    float b2v = bf2f((unsigned short)(ub.y & 0xffff));
    float b3v = bf2f((unsigned short)(ub.y >> 16));
    #pragma unroll
    for (int i = 0; i < 2; ++i) {
      f32x4 wv = *(const f32x4*)(w2t + (q * 2 + i) * HDIM + k);
      za[i] += a0 * wv[0] + a1 * wv[1] + a2 * wv[2] + a3 * wv[3];
      zb[i] += b0v * wv[0] + b1v * wv[1] + b2v * wv[2] + b3v * wv[3];
    }
  }

  float d = 0.0f, na2 = 0.0f, nb2 = 0.0f;
  #pragma unroll
  for (int i = 0; i < 2; ++i) {
    float ua = tanh_fast(za[i]);
    float ub = tanh_fast(zb[i]);
    d   += ua * ub;
    na2 += ua * ua;
    nb2 += ub * ub;
  }
  d   += __shfl_xor(d, 1);   d   += __shfl_xor(d, 2);   d   += __shfl_xor(d, 4);
  na2 += __shfl_xor(na2, 1); na2 += __shfl_xor(na2, 2); na2 += __shfl_xor(na2, 4);
  nb2 += __shfl_xor(nb2, 1); nb2 += __shfl_xor(nb2, 2); nb2 += __shfl_xor(nb2, 4);

  if (q == 0) {
    float den = fmaxf(sqrtf(na2), 1e-8f) * fmaxf(sqrtf(nb2), 1e-8f);
    float ov  = d / den;
    float fid = ov * ov;
    out[blockIdx.x * NPAIR + p] = fminf(fid, 1.0f);
  }
}

extern "C" void kernel_launch(void* const* d_in, const int* in_sizes, int n_in,
                              void* d_out, int out_size, void* d_ws, size_t ws_size,
                              hipStream_t stream) {
  const float* img_a = (const float*)d_in[0];
  const float* img_b = (const float*)d_in[1];
  const float* W1    = (const float*)d_in[2];
  const float* b1    = (const float*)d_in[3];
  const float* W2    = (const float*)d_in[4];
  const float* b2    = (const float*)d_in[5];
  // d_in[6] = theta: unused — the circuit is unitary, fidelity is invariant.

  unsigned short* w1s = (unsigned short*)d_ws;
  float* w2t = (float*)((char*)d_ws + W1S_BYTES);

  prep_kernel<<<(W1S_ELEMS + 255) / 256, 256, 0, stream>>>(W1, W2, w1s, w2t);

  const int n_pairs = out_size;              // 65536
  qcm_kernel<<<n_pairs / NPAIR, 64, 0, stream>>>(img_a, img_b, b1, b2, w1s, w2t,
                                                 (float*)d_out);
}

// Round 4
// 123.393 us; speedup vs baseline: 1.3684x; 1.3684x over previous
//
#include <hip/hip_runtime.h>

// =============================================================================
// QuantumContrastiveModel — mathematical reduction:
//   StronglyEntanglingLayers is a fixed 16x16 UNITARY applied to BOTH states;
//   fidelity |<U va|U vb>|^2 = (va.vb)^2 — the circuit cancels, theta unused.
//   With u = tanh(relu(x@W1+b1)@W2+b2):
//     fid = clip( (ua.ub)^2 / (max(|ua|,1e-8)*max(|ub|,1e-8))^2, 0, 1 )
//   R2 (117us) == R4 (118us, W off VMEM): A-stream alone costs 117us
//     -> 212MB HBM / 117us = 1.8 TB/s = random-128B page-miss ceiling.
//     A-fragment loads are structurally 128B-per-row @ stride 3136B.
//   R5 (169us): sequential staging CONFOUNDED by 6 waves/CU + 2x W + serial
//     phases. Inconclusive on the page theory.
//   R6: split-K. 16 pairs/block, 4 waves share the SAME 32 rows, each wave
//     owns a K-quarter (steps {7,6,6,6}). Staging reads WHOLE rows as 1KB
//     lane-contiguous bursts (depth-2 pipeline) -> bf16 LDS slab 51.7KB ->
//     3 blocks/CU = 12 waves/CU (R2's proven-sufficient occupancy). W traffic
//     unchanged vs R2 (100KB/16 pairs, split across waves). Partial accs
//     reduced via LDS (Rbuf reuses slab), verified epilogue/phase-2 kept.
// =============================================================================

#define KDIM   784
#define HDIM   64
#define KSTEPS 25                        // ceil(784/32); last step zero-padded
#define W1S_ELEMS (KSTEPS * 4 * 64 * 8)  // 51200 bf16 in B-fragment order
#define W1S_BYTES (W1S_ELEMS * 2)        // 102400 bytes

#define LROWS  808                       // shorts per A-slab row (1616 B):
                                         // fragment ds_read_b128 is uniform
                                         // 8-access/bank (minimum) at this stride
#define A_SLAB_BYTES (32 * LROWS * 2)    // 51712 B -> 3 blocks/CU
#define H_OFF  32768                     // H sits after the 32KB reduce buffer

typedef float  f32x4  __attribute__((ext_vector_type(4)));
typedef short  bf16x8 __attribute__((ext_vector_type(8)));

__device__ __forceinline__ unsigned short f2bf(float f) {
  unsigned u = __float_as_uint(f);
  u += 0x7fffu + ((u >> 16) & 1u);       // round-to-nearest-even
  return (unsigned short)(u >> 16);
}

__device__ __forceinline__ float bf2f(unsigned short h) {
  return __uint_as_float(((unsigned)h) << 16);
}

__device__ __forceinline__ uint2 pack4(f32x4 v) {
  uint2 r;
  r.x = (unsigned)f2bf(v[0]) | ((unsigned)f2bf(v[1]) << 16);
  r.y = (unsigned)f2bf(v[2]) | ((unsigned)f2bf(v[3]) << 16);
  return r;
}

__device__ __forceinline__ float tanh_fast(float x) {
  float e = __expf(2.0f * x);
  return 1.0f - 2.0f / (e + 1.0f);       // exact limits at +-inf
}

// --- prep: W1 (784x64 f32) -> bf16 in MFMA B-fragment order, K padded to 800;
//           W2 (64x16) -> transposed (16x64) f32.  (unchanged, verified)
__global__ __launch_bounds__(256)
void prep_kernel(const float* __restrict__ W1, const float* __restrict__ W2,
                 unsigned short* __restrict__ w1s, float* __restrict__ w2t) {
  int tid = blockIdx.x * 256 + threadIdx.x;
  if (tid < W1S_ELEMS) {
    int j  = tid & 7;            // element within 8-wide fragment
    int l  = (tid >> 3) & 63;    // lane
    int st = tid >> 9;           // s*4 + t
    int s  = st >> 2;
    int t  = st & 3;
    int k  = s * 32 + (l >> 4) * 8 + j;   // B[k][n]: k = quad*8+j
    int n  = t * 16 + (l & 15);           //          n = lane&15
    float v = (k < KDIM) ? W1[k * HDIM + n] : 0.0f;
    w1s[tid] = f2bf(v);
  }
  if (tid < HDIM * 16) {
    int c = tid >> 6;            // 0..15
    int k = tid & 63;            // 0..63
    w2t[c * HDIM + k] = W2[k * 16 + c];
  }
}

// --- main: 256 threads = 4 waves; 16 pairs/block; waves split K.
__global__ __launch_bounds__(256, 3)
void qcm_kernel(const float* __restrict__ img_a, const float* __restrict__ img_b,
                const float* __restrict__ b1,    const float* __restrict__ b2,
                const unsigned short* __restrict__ w1s,
                const float* __restrict__ w2t,
                float* __restrict__ out) {
  // [0,51712): A-slab 32 x 808 bf16. Reused after K-loop:
  //   [0,32768): Rbuf f32[4 waves][32 vals][64 lanes]; [32768,+4608): H 32x72 bf16.
  __shared__ __attribute__((aligned(16))) char smem[A_SLAB_BYTES];
  unsigned short (*L)[LROWS] = (unsigned short(*)[LROWS])smem;

  const int tid  = threadIdx.x;
  const int wave = tid >> 6;
  const int lane = tid & 63;
  const int m    = lane & 15;
  const int quad = lane >> 4;
  const int p0   = blockIdx.x * 16;

  // ---- stage 32 whole rows (16 a + 16 b) as sequential 1KB bursts ----
  // wave w stages a-rows 4w..4w+3 and b-rows 4w..4w+3; depth-2 row pipeline.
  {
    const float* aB = img_a + (size_t)p0 * KDIM;
    const float* bB = img_b + (size_t)p0 * KDIM;
    f32x4 z; z[0] = z[1] = z[2] = z[3] = 0.0f;

    const float* rp = aB + (size_t)(4 * wave) * KDIM;   // row-task 0
    f32x4 c0 = *(const f32x4*)(rp + lane * 4);
    f32x4 c1 = *(const f32x4*)(rp + 256 + lane * 4);
    f32x4 c2 = *(const f32x4*)(rp + 512 + lane * 4);
    f32x4 ct = z;
    if (lane < 4) ct = *(const f32x4*)(rp + 768 + lane * 4);

    #pragma unroll
    for (int t = 0; t < 8; ++t) {                       // tasks 0-3 = a, 4-7 = b
      f32x4 n0 = z, n1 = z, n2 = z, nt = z;
      if (t < 7) {
        const int tn = t + 1;
        const float* np = ((tn >> 2) ? bB : aB) + (size_t)(4 * wave + (tn & 3)) * KDIM;
        n0 = *(const f32x4*)(np + lane * 4);
        n1 = *(const f32x4*)(np + 256 + lane * 4);
        n2 = *(const f32x4*)(np + 512 + lane * 4);
        if (lane < 4) nt = *(const f32x4*)(np + 768 + lane * 4);
      }
      const int lr = (t >> 2) * 16 + 4 * wave + (t & 3);  // 0-15 a, 16-31 b
      *(uint2*)&L[lr][lane * 4]       = pack4(c0);
      *(uint2*)&L[lr][256 + lane * 4] = pack4(c1);
      *(uint2*)&L[lr][512 + lane * 4] = pack4(c2);
      if (lane < 4) *(uint2*)&L[lr][768 + lane * 4] = pack4(ct);
      c0 = n0; c1 = n1; c2 = n2; ct = nt;
    }
    if (tid < 128) {                     // zero K-pad shorts 784..799, all rows
      uint2 z2; z2.x = 0u; z2.y = 0u;
      *(uint2*)&L[tid >> 2][784 + (tid & 3) * 4] = z2;
    }
  }
  __syncthreads();

  // ---- K-loop: wave w owns steps {0-6, 7-12, 13-18, 19-24} ----
  f32x4 accA[4], accB[4];
  #pragma unroll
  for (int t = 0; t < 4; ++t) {
    accA[t][0] = accA[t][1] = accA[t][2] = accA[t][3] = 0.0f;
    accB[t][0] = accB[t][1] = accB[t][2] = accB[t][3] = 0.0f;
  }

  const int4* bwl = (const int4*)w1s + lane;
  const int s0   = wave ? (6 * wave + 1) : 0;
  const int scnt = wave ? 6 : 7;

  int4 w0 = bwl[s0 * 256];
  int4 w1 = bwl[s0 * 256 + 64];
  int4 w2 = bwl[s0 * 256 + 128];
  int4 w3 = bwl[s0 * 256 + 192];
  bf16x8 aA = *(const bf16x8*)&L[m][s0 * 32 + quad * 8];
  bf16x8 aB = *(const bf16x8*)&L[16 + m][s0 * 32 + quad * 8];

  for (int i = 0; i < scnt; ++i) {
    const int sp = (i + 1 < scnt) ? s0 + i + 1 : s0 + i;   // tail: redundant
    int4 nw0 = bwl[sp * 256];
    int4 nw1 = bwl[sp * 256 + 64];
    int4 nw2 = bwl[sp * 256 + 128];
    int4 nw3 = bwl[sp * 256 + 192];
    bf16x8 nA = *(const bf16x8*)&L[m][sp * 32 + quad * 8];
    bf16x8 nB = *(const bf16x8*)&L[16 + m][sp * 32 + quad * 8];

    accA[0] = __builtin_amdgcn_mfma_f32_16x16x32_bf16(
        aA, __builtin_bit_cast(bf16x8, w0), accA[0], 0, 0, 0);
    accB[0] = __builtin_amdgcn_mfma_f32_16x16x32_bf16(
        aB, __builtin_bit_cast(bf16x8, w0), accB[0], 0, 0, 0);
    accA[1] = __builtin_amdgcn_mfma_f32_16x16x32_bf16(
        aA, __builtin_bit_cast(bf16x8, w1), accA[1], 0, 0, 0);
    accB[1] = __builtin_amdgcn_mfma_f32_16x16x32_bf16(
        aB, __builtin_bit_cast(bf16x8, w1), accB[1], 0, 0, 0);
    accA[2] = __builtin_amdgcn_mfma_f32_16x16x32_bf16(
        aA, __builtin_bit_cast(bf16x8, w2), accA[2], 0, 0, 0);
    accB[2] = __builtin_amdgcn_mfma_f32_16x16x32_bf16(
        aB, __builtin_bit_cast(bf16x8, w2), accB[2], 0, 0, 0);
    accA[3] = __builtin_amdgcn_mfma_f32_16x16x32_bf16(
        aA, __builtin_bit_cast(bf16x8, w3), accA[3], 0, 0, 0);
    accB[3] = __builtin_amdgcn_mfma_f32_16x16x32_bf16(
        aB, __builtin_bit_cast(bf16x8, w3), accB[3], 0, 0, 0);

    w0 = nw0; w1 = nw1; w2 = nw2; w3 = nw3;
    aA = nA;  aB = nB;
  }
  __syncthreads();                      // all waves done reading the A-slab

  // ---- cross-wave K-reduction via LDS ----
  // Rbuf[w][v][lane] f32: v = t*4+j (accA) / 16 + t*4+j (accB)
  float* R = (float*)smem;
  #pragma unroll
  for (int t = 0; t < 4; ++t) {
    #pragma unroll
    for (int j = 0; j < 4; ++j) {
      R[(wave * 32 + t * 4 + j)      * 64 + lane] = accA[t][j];
      R[(wave * 32 + 16 + t * 4 + j) * 64 + lane] = accB[t][j];
    }
  }
  __syncthreads();

  // wave w reduces v = 8w..8w+8 and writes H (bias+relu, verified C-frag map)
  unsigned short (*H)[72] = (unsigned short(*)[72])(smem + H_OFF);
  #pragma unroll
  for (int i = 0; i < 8; ++i) {
    const int v = wave * 8 + i;
    float sum = R[(0 * 32 + v) * 64 + lane] + R[(1 * 32 + v) * 64 + lane]
              + R[(2 * 32 + v) * 64 + lane] + R[(3 * 32 + v) * 64 + lane];
    const int j = v & 3;
    const int t = (v >> 2) & 3;
    const int row = ((v < 16) ? 0 : 16) + quad * 4 + j;   // pair row; a/b half
    float h = fmaxf(sum + b1[t * 16 + m], 0.0f);
    H[row][t * 16 + m] = f2bf(h);
  }
  __syncthreads();

  // ---- phase 2: 16 pairs x 8 threads/pair (tid < 128); 2 z-cols each ----
  if (tid < 128) {
    const int p = tid >> 3;            // 0..15 local pair
    const int q = tid & 7;             // cols q*2, q*2+1
    const unsigned short* ha_row = &H[p][0];
    const unsigned short* hb_row = &H[16 + p][0];

    float za[2], zb[2];
    za[0] = b2[q * 2];     zb[0] = za[0];
    za[1] = b2[q * 2 + 1]; zb[1] = za[1];

    for (int k = 0; k < HDIM; k += 4) {
      uint2 ua = *(const uint2*)(ha_row + k);
      uint2 ub = *(const uint2*)(hb_row + k);
      float a0 = bf2f((unsigned short)(ua.x & 0xffff));
      float a1 = bf2f((unsigned short)(ua.x >> 16));
      float a2 = bf2f((unsigned short)(ua.y & 0xffff));
      float a3 = bf2f((unsigned short)(ua.y >> 16));
      float b0v = bf2f((unsigned short)(ub.x & 0xffff));
      float b1v = bf2f((unsigned short)(ub.x >> 16));
      float b2v = bf2f((unsigned short)(ub.y & 0xffff));
      float b3v = bf2f((unsigned short)(ub.y >> 16));
      #pragma unroll
      for (int i = 0; i < 2; ++i) {
        f32x4 wv = *(const f32x4*)(w2t + (q * 2 + i) * HDIM + k);
        za[i] += a0 * wv[0] + a1 * wv[1] + a2 * wv[2] + a3 * wv[3];
        zb[i] += b0v * wv[0] + b1v * wv[1] + b2v * wv[2] + b3v * wv[3];
      }
    }

    float d = 0.0f, na2 = 0.0f, nb2 = 0.0f;
    #pragma unroll
    for (int i = 0; i < 2; ++i) {
      float ua = tanh_fast(za[i]);
      float ub = tanh_fast(zb[i]);
      d   += ua * ub;
      na2 += ua * ua;
      nb2 += ub * ub;
    }
    d   += __shfl_xor(d, 1);   d   += __shfl_xor(d, 2);   d   += __shfl_xor(d, 4);
    na2 += __shfl_xor(na2, 1); na2 += __shfl_xor(na2, 2); na2 += __shfl_xor(na2, 4);
    nb2 += __shfl_xor(nb2, 1); nb2 += __shfl_xor(nb2, 2); nb2 += __shfl_xor(nb2, 4);

    if (q == 0) {
      float den = fmaxf(sqrtf(na2), 1e-8f) * fmaxf(sqrtf(nb2), 1e-8f);
      float ov  = d / den;
      float fid = ov * ov;
      out[blockIdx.x * 16 + p] = fminf(fid, 1.0f);
    }
  }
}

extern "C" void kernel_launch(void* const* d_in, const int* in_sizes, int n_in,
                              void* d_out, int out_size, void* d_ws, size_t ws_size,
                              hipStream_t stream) {
  const float* img_a = (const float*)d_in[0];
  const float* img_b = (const float*)d_in[1];
  const float* W1    = (const float*)d_in[2];
  const float* b1    = (const float*)d_in[3];
  const float* W2    = (const float*)d_in[4];
  const float* b2    = (const float*)d_in[5];
  // d_in[6] = theta: unused — the circuit is unitary, fidelity is invariant.

  unsigned short* w1s = (unsigned short*)d_ws;
  float* w2t = (float*)((char*)d_ws + W1S_BYTES);

  prep_kernel<<<(W1S_ELEMS + 255) / 256, 256, 0, stream>>>(W1, W2, w1s, w2t);

  const int n_pairs = out_size;              // 65536
  qcm_kernel<<<n_pairs / 16, 256, 0, stream>>>(img_a, img_b, b1, b2, w1s, w2t,
                                               (float*)d_out);
}

// Round 5
// 113.818 us; speedup vs baseline: 1.4835x; 1.0841x over previous
//
#include <hip/hip_runtime.h>

// =============================================================================
// QuantumContrastiveModel — mathematical reduction:
//   StronglyEntanglingLayers is a fixed 16x16 UNITARY applied to BOTH states;
//   fidelity |<U va|U vb>|^2 = (va.vb)^2 — the circuit cancels, theta unused.
//   With u = tanh(relu(x@W1+b1)@W2+b2):
//     fid = clip( (ua.ub)^2 / (max(|ua|,1e-8)*max(|ub|,1e-8))^2, 0, 1 )
//   R2..R6 matrix: pattern (scattered vs sequential), occupancy (6..21 w/CU),
//   W-path (L2 vs LDS) ALL null. Invariant: ~40-56 KB in-flight HBM bytes/CU,
//   and BW tracked in-flight, not structure -> latency-bound hypothesis:
//   BW = inflight/latency with loaded latency ~2-3us. vmcnt is IN-ORDER, so
//   R2 exposed full HBM latency each K-step (W+A share the counter).
//   R7 (discriminator): R3's packed a|b fragment (8 pairs/wave, 2 loads/step)
//   + R4's W-in-LDS (A-loads are the ONLY VMEM -> clean vmcnt stream)
//   + depth-5 pipeline via fully-unrolled K-loop, static 6-slot reg file.
//   1024-thr blocks, 16 waves, 128 pairs; in-flight 160 KB/CU = 3.3x invariant.
//   Flat result => platform read-service cap; declare roofline.
// =============================================================================

#define KDIM   784
#define HDIM   64
#define KSTEPS 25                        // ceil(784/32); last step zero-padded
#define W1S_ELEMS (KSTEPS * 4 * 64 * 8)  // 51200 bf16 in B-fragment order
#define W1S_BYTES (W1S_ELEMS * 2)        // 102400 bytes
#define W1S_INT4  (W1S_BYTES / 16)       // 6400 int4

typedef float  f32x4  __attribute__((ext_vector_type(4)));
typedef short  bf16x8 __attribute__((ext_vector_type(8)));

__device__ __forceinline__ unsigned short f2bf(float f) {
  unsigned u = __float_as_uint(f);
  u += 0x7fffu + ((u >> 16) & 1u);       // round-to-nearest-even
  return (unsigned short)(u >> 16);
}

__device__ __forceinline__ float bf2f(unsigned short h) {
  return __uint_as_float(((unsigned)h) << 16);
}

__device__ __forceinline__ bf16x8 cvt8(f32x4 lo, f32x4 hi) {
  bf16x8 r;
  r[0] = (short)f2bf(lo[0]); r[1] = (short)f2bf(lo[1]);
  r[2] = (short)f2bf(lo[2]); r[3] = (short)f2bf(lo[3]);
  r[4] = (short)f2bf(hi[0]); r[5] = (short)f2bf(hi[1]);
  r[6] = (short)f2bf(hi[2]); r[7] = (short)f2bf(hi[3]);
  return r;
}

__device__ __forceinline__ float tanh_fast(float x) {
  float e = __expf(2.0f * x);
  return 1.0f - 2.0f / (e + 1.0f);       // exact limits at +-inf
}

// --- prep: W1 (784x64 f32) -> bf16 in MFMA B-fragment order, K padded to 800;
//           W2 (64x16) -> transposed (16x64) f32.  (unchanged, verified)
__global__ __launch_bounds__(256)
void prep_kernel(const float* __restrict__ W1, const float* __restrict__ W2,
                 unsigned short* __restrict__ w1s, float* __restrict__ w2t) {
  int tid = blockIdx.x * 256 + threadIdx.x;
  if (tid < W1S_ELEMS) {
    int j  = tid & 7;            // element within 8-wide fragment
    int l  = (tid >> 3) & 63;    // lane
    int st = tid >> 9;           // s*4 + t
    int s  = st >> 2;
    int t  = st & 3;
    int k  = s * 32 + (l >> 4) * 8 + j;   // B[k][n]: k = quad*8+j
    int n  = t * 16 + (l & 15);           //          n = lane&15
    float v = (k < KDIM) ? W1[k * HDIM + n] : 0.0f;
    w1s[tid] = f2bf(v);
  }
  if (tid < HDIM * 16) {
    int c = tid >> 6;            // 0..15
    int k = tid & 63;            // 0..63
    w2t[c * HDIM + k] = W2[k * 16 + c];
  }
}

// --- main: 1024 threads = 16 waves; 8 pairs/wave (packed a|b fragment);
//     128 pairs/block; grid = 512. W staged in LDS once per block.
__global__ __launch_bounds__(1024, 4)
void qcm_kernel(const float* __restrict__ img_a, const float* __restrict__ img_b,
                const float* __restrict__ b1,    const float* __restrict__ b2,
                const unsigned short* __restrict__ w1s,
                const float* __restrict__ w2t,
                float* __restrict__ out) {
  // 100KB: W1 fragments during the K-loop, then REUSED as H[256][72] (36.9KB).
  __shared__ __attribute__((aligned(16))) char smem[W1S_BYTES];

  const int tid = threadIdx.x;

  // ---- one-shot stage of w1s into LDS (coalesced int4 copy; R4-verified) ----
  {
    const int4* src = (const int4*)w1s;
    int4* dst = (int4*)smem;
    #pragma unroll
    for (int i = 0; i < 7; ++i) {
      int idx = tid + i * 1024;
      if (idx < W1S_INT4) dst[idx] = src[idx];
    }
  }
  __syncthreads();

  const int wave = tid >> 6;      // 0..15
  const int lane = tid & 63;
  const int m    = lane & 15;     // A-frag row: 0-7 -> a pair m, 8-15 -> b pair m-8
  const int quad = lane >> 4;
  const int p0   = blockIdx.x * 128 + wave * 8;

  // packed a|b: one row pointer per lane (R3-verified layout)
  const float* row = (m < 8)
      ? (img_a + (size_t)(p0 + m)     * KDIM)
      : (img_b + (size_t)(p0 + m - 8) * KDIM);
  const int koff = quad * 8;      // A-frag k-offset: k = quad*8 + j

  f32x4 acc[4];
  #pragma unroll
  for (int t = 0; t < 4; ++t)
    acc[t][0] = acc[t][1] = acc[t][2] = acc[t][3] = 0.0f;

  const int4* wl = (const int4*)smem;   // W fragments in LDS

  f32x4 z4; z4[0] = z4[1] = z4[2] = z4[3] = 0.0f;

  // ---- depth-5 pipeline: 6-slot static register file, fully unrolled ----
  f32x4 pip[6][2];
  #pragma unroll
  for (int i = 0; i < 6; ++i) { pip[i][0] = z4; pip[i][1] = z4; }

  // prologue: issue batches 0..4 (all < 24 -> full loads)
  #pragma unroll
  for (int st = 0; st < 5; ++st) {
    const int kb = st * 32 + koff;
    pip[st][0] = *(const f32x4*)(row + kb);
    pip[st][1] = *(const f32x4*)(row + kb + 4);
  }

  #pragma unroll
  for (int s = 0; s < KSTEPS; ++s) {
    // issue batch s+5 into slot (s+5)%6 (the slot consumed last iteration)
    {
      const int st = s + 5;
      const int slot = st % 6;
      if (st < 24) {
        const int kb = st * 32 + koff;
        pip[slot][0] = *(const f32x4*)(row + kb);
        pip[slot][1] = *(const f32x4*)(row + kb + 4);
      } else if (st == 24) {
        // tail: k=768..799; quads 2,3 past 784 -> zero (w1s rows 0 there too)
        if (quad < 2) {
          pip[slot][0] = *(const f32x4*)(row + 768 + koff);
          pip[slot][1] = *(const f32x4*)(row + 768 + koff + 4);
        } else {
          pip[slot][0] = z4; pip[slot][1] = z4;
        }
      }
      // st > 24: slot never consumed again — leave as is
    }

    // W fragments from LDS (lgkmcnt stream — independent of vmcnt)
    const int base = s * 256 + lane;
    int4 w0 = wl[base];
    int4 w1 = wl[base + 64];
    int4 w2 = wl[base + 128];
    int4 w3 = wl[base + 192];

    // consume batch s: waits vmcnt<=10 (batches s+1..s+5 stay in flight)
    bf16x8 fa = cvt8(pip[s % 6][0], pip[s % 6][1]);

    acc[0] = __builtin_amdgcn_mfma_f32_16x16x32_bf16(
        fa, __builtin_bit_cast(bf16x8, w0), acc[0], 0, 0, 0);
    acc[1] = __builtin_amdgcn_mfma_f32_16x16x32_bf16(
        fa, __builtin_bit_cast(bf16x8, w1), acc[1], 0, 0, 0);
    acc[2] = __builtin_amdgcn_mfma_f32_16x16x32_bf16(
        fa, __builtin_bit_cast(bf16x8, w2), acc[2], 0, 0, 0);
    acc[3] = __builtin_amdgcn_mfma_f32_16x16x32_bf16(
        fa, __builtin_bit_cast(bf16x8, w3), acc[3], 0, 0, 0);
  }

  // all W reads done before smem is repurposed as the h-buffer
  __syncthreads();
  unsigned short (*H)[72] = (unsigned short(*)[72])smem;  // 256x72 = 36.9KB

  // epilogue: bias + relu (C-frag: row=quad*4+j -> 0-7 a / 8-15 b; col=t*16+m)
  #pragma unroll
  for (int t = 0; t < 4; ++t) {
    float bias = b1[t * 16 + m];
    #pragma unroll
    for (int j = 0; j < 4; ++j) {
      float h = fmaxf(acc[t][j] + bias, 0.0f);
      H[wave * 16 + quad * 4 + j][t * 16 + m] = f2bf(h);
    }
  }
  __syncthreads();

  // ---- phase 2: 8 threads/pair; each computes 2 of 16 z-cols for a and b ----
  const int p = tid >> 3;            // 0..127 local pair
  const int q = tid & 7;             // cols q*2, q*2+1
  const int wsrc = p >> 3;
  const int r = p & 7;
  const unsigned short* ha_row = &H[wsrc * 16 + r][0];
  const unsigned short* hb_row = &H[wsrc * 16 + 8 + r][0];

  float za[2], zb[2];
  za[0] = b2[q * 2];     zb[0] = za[0];
  za[1] = b2[q * 2 + 1]; zb[1] = za[1];

  for (int k = 0; k < HDIM; k += 4) {
    uint2 ua = *(const uint2*)(ha_row + k);
    uint2 ub = *(const uint2*)(hb_row + k);
    float a0 = bf2f((unsigned short)(ua.x & 0xffff));
    float a1 = bf2f((unsigned short)(ua.x >> 16));
    float a2 = bf2f((unsigned short)(ua.y & 0xffff));
    float a3 = bf2f((unsigned short)(ua.y >> 16));
    float b0v = bf2f((unsigned short)(ub.x & 0xffff));
    float b1v = bf2f((unsigned short)(ub.x >> 16));
    float b2v = bf2f((unsigned short)(ub.y & 0xffff));
    float b3v = bf2f((unsigned short)(ub.y >> 16));
    #pragma unroll
    for (int i = 0; i < 2; ++i) {
      f32x4 wv = *(const f32x4*)(w2t + (q * 2 + i) * HDIM + k);
      za[i] += a0 * wv[0] + a1 * wv[1] + a2 * wv[2] + a3 * wv[3];
      zb[i] += b0v * wv[0] + b1v * wv[1] + b2v * wv[2] + b3v * wv[3];
    }
  }

  float d = 0.0f, na2 = 0.0f, nb2 = 0.0f;
  #pragma unroll
  for (int i = 0; i < 2; ++i) {
    float ua = tanh_fast(za[i]);
    float ub = tanh_fast(zb[i]);
    d   += ua * ub;
    na2 += ua * ua;
    nb2 += ub * ub;
  }
  d   += __shfl_xor(d, 1);   d   += __shfl_xor(d, 2);   d   += __shfl_xor(d, 4);
  na2 += __shfl_xor(na2, 1); na2 += __shfl_xor(na2, 2); na2 += __shfl_xor(na2, 4);
  nb2 += __shfl_xor(nb2, 1); nb2 += __shfl_xor(nb2, 2); nb2 += __shfl_xor(nb2, 4);

  if (q == 0) {
    float den = fmaxf(sqrtf(na2), 1e-8f) * fmaxf(sqrtf(nb2), 1e-8f);
    float ov  = d / den;
    float fid = ov * ov;
    out[blockIdx.x * 128 + p] = fminf(fid, 1.0f);
  }
}

extern "C" void kernel_launch(void* const* d_in, const int* in_sizes, int n_in,
                              void* d_out, int out_size, void* d_ws, size_t ws_size,
                              hipStream_t stream) {
  const float* img_a = (const float*)d_in[0];
  const float* img_b = (const float*)d_in[1];
  const float* W1    = (const float*)d_in[2];
  const float* b1    = (const float*)d_in[3];
  const float* W2    = (const float*)d_in[4];
  const float* b2    = (const float*)d_in[5];
  // d_in[6] = theta: unused — the circuit is unitary, fidelity is invariant.

  unsigned short* w1s = (unsigned short*)d_ws;
  float* w2t = (float*)((char*)d_ws + W1S_BYTES);

  prep_kernel<<<(W1S_ELEMS + 255) / 256, 256, 0, stream>>>(W1, W2, w1s, w2t);

  const int n_pairs = out_size;              // 65536
  qcm_kernel<<<n_pairs / 128, 1024, 0, stream>>>(img_a, img_b, b1, b2, w1s, w2t,
                                                 (float*)d_out);
}

// Round 7
// 112.639 us; speedup vs baseline: 1.4991x; 1.0105x over previous
//
#include <hip/hip_runtime.h>

// =============================================================================
// QuantumContrastiveModel — mathematical reduction:
//   StronglyEntanglingLayers is a fixed 16x16 UNITARY applied to BOTH states;
//   fidelity |<U va|U vb>|^2 = (va.vb)^2 — the circuit cancels, theta unused.
//   With u = tanh(relu(x@W1+b1)@W2+b2):
//     fid = clip( (ua.ub)^2 / (max(|ua|,1e-8)*max(|ub|,1e-8))^2, 0, 1 )
//   R2..R7: pattern / occupancy / W-path all null at ~114-117us = 3.6 TB/s
//     aggregate read. In-flight bytes/CU (~40-56KB) is the invariant.
//   R8 FAILED (absmax 1.0): separate asm-volatile loads + C-level consume is
//     unsound — compiler copies rotating-slot regs before data lands.
//   R9 (sound discriminator): vmcnt completes IN-ORDER, so W (L2, depth-1)
//     consumption forces earlier A-loads complete -> A-depth is capped at
//     W-depth. Fix: prefetch BOTH W and A two batches ahead in a 3-slot
//     register file (compile-time indices, full unroll), sched_barrier(0)
//     after each issue block so loads cannot sink to use (R7 collapse).
//     Normal IR loads -> compiler emits exact counted vmcnt. 16KB/wave
//     in flight x 12 waves/CU = ~190KB/CU = 4x invariant.
//     Gate: VGPR 135-168. Flat result with gates met => service-cap roofline.
// =============================================================================

#define KDIM   784
#define HDIM   64
#define KSTEPS 25                        // ceil(784/32); last step zero-padded
#define W1S_ELEMS (KSTEPS * 4 * 64 * 8)  // 51200 bf16 in B-fragment order
#define W1S_BYTES (W1S_ELEMS * 2)        // 102400 bytes

typedef float  f32x4  __attribute__((ext_vector_type(4)));
typedef short  bf16x8 __attribute__((ext_vector_type(8)));

__device__ __forceinline__ unsigned short f2bf(float f) {
  unsigned u = __float_as_uint(f);
  u += 0x7fffu + ((u >> 16) & 1u);       // round-to-nearest-even
  return (unsigned short)(u >> 16);
}

__device__ __forceinline__ float bf2f(unsigned short h) {
  return __uint_as_float(((unsigned)h) << 16);
}

__device__ __forceinline__ bf16x8 cvt8(f32x4 lo, f32x4 hi) {
  bf16x8 r;
  r[0] = (short)f2bf(lo[0]); r[1] = (short)f2bf(lo[1]);
  r[2] = (short)f2bf(lo[2]); r[3] = (short)f2bf(lo[3]);
  r[4] = (short)f2bf(hi[0]); r[5] = (short)f2bf(hi[1]);
  r[6] = (short)f2bf(hi[2]); r[7] = (short)f2bf(hi[3]);
  return r;
}

__device__ __forceinline__ float tanh_fast(float x) {
  float e = __expf(2.0f * x);
  return 1.0f - 2.0f / (e + 1.0f);       // exact limits at +-inf
}

// --- prep: W1 (784x64 f32) -> bf16 in MFMA B-fragment order, K padded to 800;
//           W2 (64x16) -> transposed (16x64) f32.  (unchanged, verified)
__global__ __launch_bounds__(256)
void prep_kernel(const float* __restrict__ W1, const float* __restrict__ W2,
                 unsigned short* __restrict__ w1s, float* __restrict__ w2t) {
  int tid = blockIdx.x * 256 + threadIdx.x;
  if (tid < W1S_ELEMS) {
    int j  = tid & 7;            // element within 8-wide fragment
    int l  = (tid >> 3) & 63;    // lane
    int st = tid >> 9;           // s*4 + t
    int s  = st >> 2;
    int t  = st & 3;
    int k  = s * 32 + (l >> 4) * 8 + j;   // B[k][n]: k = quad*8+j
    int n  = t * 16 + (l & 15);           //          n = lane&15
    float v = (k < KDIM) ? W1[k * HDIM + n] : 0.0f;
    w1s[tid] = f2bf(v);
  }
  if (tid < HDIM * 16) {
    int c = tid >> 6;            // 0..15
    int k = tid & 63;            // 0..63
    w2t[c * HDIM + k] = W2[k * 16 + c];
  }
}

// --- main: 256 threads = 4 waves; 16 pairs/wave; 64 pairs/block; grid = 1024.
//     Symmetric depth-2 register pipeline for BOTH W (L2) and A (HBM).
__global__ __launch_bounds__(256, 3)
void qcm_kernel(const float* __restrict__ img_a, const float* __restrict__ img_b,
                const float* __restrict__ b1,    const float* __restrict__ b2,
                const unsigned short* __restrict__ w1s,
                const float* __restrict__ w2t,
                float* __restrict__ out) {
  __shared__ __attribute__((aligned(16))) unsigned short lds_h[128][72]; // 18.4KB

  const int tid  = threadIdx.x;
  const int wave = tid >> 6;
  const int lane = tid & 63;
  const int m    = lane & 15;     // A-frag row / C-frag col
  const int quad = lane >> 4;
  const int p0   = blockIdx.x * 64 + wave * 16;

  const float* rowA = img_a + (size_t)(p0 + m) * KDIM;
  const float* rowB = img_b + (size_t)(p0 + m) * KDIM;
  const int koff = quad * 8;      // A-frag k-offset: k = quad*8 + j

  f32x4 accA[4], accB[4];
  #pragma unroll
  for (int t = 0; t < 4; ++t) {
    accA[t][0] = accA[t][1] = accA[t][2] = accA[t][3] = 0.0f;
    accB[t][0] = accB[t][1] = accB[t][2] = accB[t][3] = 0.0f;
  }

  const int4* bwl = (const int4*)w1s + lane;

  // ---- 3-slot register pipeline (all slot indices compile-time) ----
  f32x4 A0[3], A1[3], B0[3], B1[3];     // A-rows: a-side and b-side
  int4  W0[3], W1r[3], W2r[3], W3r[3];  // W fragments

  // issue batch st into slot sl (st, sl compile-time after unroll)
  auto issue = [&](int st, int sl) __attribute__((always_inline)) {
    if (st > 24) return;
    const float *pa, *pb;
    if (st < 24) {
      pa = rowA + st * 32 + koff;
      pb = rowB + st * 32 + koff;
    } else {
      // tail: quads 0,1 read k=768..783 (real); quads 2,3 read row start
      // (garbage) — multiplied by w1s rows k=784..799 which are ZERO.
      const int off = (quad < 2) ? (768 + koff) : 0;
      pa = rowA + off;
      pb = rowB + off;
    }
    A0[sl] = *(const f32x4*)pa;
    A1[sl] = *(const f32x4*)(pa + 4);
    B0[sl] = *(const f32x4*)pb;
    B1[sl] = *(const f32x4*)(pb + 4);
    W0[sl]  = bwl[st * 256];
    W1r[sl] = bwl[st * 256 + 64];
    W2r[sl] = bwl[st * 256 + 128];
    W3r[sl] = bwl[st * 256 + 192];
  };

  // prologue: batches 0,1 in flight
  issue(0, 0);
  issue(1, 1);
  __builtin_amdgcn_sched_barrier(0);

  #pragma unroll
  for (int s = 0; s < KSTEPS; ++s) {
    // issue batch s+2 into slot (s+2)%3 (consumed at iter s-1 — free)
    issue(s + 2, (s + 2) % 3);
    // pin: loads may hoist earlier but cannot sink past this point
    __builtin_amdgcn_sched_barrier(0);

    const int sc = s % 3;
    // compiler emits exact counted vmcnt here (batches s+1, s+2 outstanding)
    bf16x8 fa = cvt8(A0[sc], A1[sc]);
    bf16x8 fb = cvt8(B0[sc], B1[sc]);

    bf16x8 wf0 = __builtin_bit_cast(bf16x8, W0[sc]);
    bf16x8 wf1 = __builtin_bit_cast(bf16x8, W1r[sc]);
    bf16x8 wf2 = __builtin_bit_cast(bf16x8, W2r[sc]);
    bf16x8 wf3 = __builtin_bit_cast(bf16x8, W3r[sc]);
    accA[0] = __builtin_amdgcn_mfma_f32_16x16x32_bf16(fa, wf0, accA[0], 0, 0, 0);
    accB[0] = __builtin_amdgcn_mfma_f32_16x16x32_bf16(fb, wf0, accB[0], 0, 0, 0);
    accA[1] = __builtin_amdgcn_mfma_f32_16x16x32_bf16(fa, wf1, accA[1], 0, 0, 0);
    accB[1] = __builtin_amdgcn_mfma_f32_16x16x32_bf16(fb, wf1, accB[1], 0, 0, 0);
    accA[2] = __builtin_amdgcn_mfma_f32_16x16x32_bf16(fa, wf2, accA[2], 0, 0, 0);
    accB[2] = __builtin_amdgcn_mfma_f32_16x16x32_bf16(fb, wf2, accB[2], 0, 0, 0);
    accA[3] = __builtin_amdgcn_mfma_f32_16x16x32_bf16(fa, wf3, accA[3], 0, 0, 0);
    accB[3] = __builtin_amdgcn_mfma_f32_16x16x32_bf16(fb, wf3, accB[3], 0, 0, 0);
  }

  // epilogue: bias + relu, park h in LDS as bf16 (C-frag: row=quad*4+j, col=lane&15)
  #pragma unroll
  for (int t = 0; t < 4; ++t) {
    float bias = b1[t * 16 + m];
    const int ra = wave * 32;
    #pragma unroll
    for (int j = 0; j < 4; ++j) {
      float ha = fmaxf(accA[t][j] + bias, 0.0f);
      float hb = fmaxf(accB[t][j] + bias, 0.0f);
      lds_h[ra +      quad * 4 + j][t * 16 + m] = f2bf(ha);
      lds_h[ra + 16 + quad * 4 + j][t * 16 + m] = f2bf(hb);
    }
  }
  __syncthreads();

  // phase 2: 4 threads per pair; each computes 4 of the 16 z-columns for a and b
  const int p = tid >> 2;            // 0..63 local pair
  const int q = tid & 3;
  const int wsrc = p >> 4;
  const int r = p & 15;
  const unsigned short* ha_row = &lds_h[wsrc * 32 + r][0];
  const unsigned short* hb_row = &lds_h[wsrc * 32 + 16 + r][0];

  float za[4], zb[4];
  #pragma unroll
  for (int i = 0; i < 4; ++i) { za[i] = b2[q * 4 + i]; zb[i] = za[i]; }

  for (int k = 0; k < HDIM; k += 4) {
    uint2 ua = *(const uint2*)(ha_row + k);
    uint2 ub = *(const uint2*)(hb_row + k);
    float a0 = bf2f((unsigned short)(ua.x & 0xffff));
    float a1 = bf2f((unsigned short)(ua.x >> 16));
    float a2 = bf2f((unsigned short)(ua.y & 0xffff));
    float a3 = bf2f((unsigned short)(ua.y >> 16));
    float b0v = bf2f((unsigned short)(ub.x & 0xffff));
    float b1v = bf2f((unsigned short)(ub.x >> 16));
    float b2v = bf2f((unsigned short)(ub.y & 0xffff));
    float b3v = bf2f((unsigned short)(ub.y >> 16));
    #pragma unroll
    for (int i = 0; i < 4; ++i) {
      f32x4 wv = *(const f32x4*)(w2t + (q * 4 + i) * HDIM + k);
      za[i] += a0 * wv[0] + a1 * wv[1] + a2 * wv[2] + a3 * wv[3];
      zb[i] += b0v * wv[0] + b1v * wv[1] + b2v * wv[2] + b3v * wv[3];
    }
  }

  float d = 0.0f, na2 = 0.0f, nb2 = 0.0f;
  #pragma unroll
  for (int i = 0; i < 4; ++i) {
    float ua = tanh_fast(za[i]);
    float ub = tanh_fast(zb[i]);
    d   += ua * ub;
    na2 += ua * ua;
    nb2 += ub * ub;
  }
  d   += __shfl_xor(d, 1);   d   += __shfl_xor(d, 2);
  na2 += __shfl_xor(na2, 1); na2 += __shfl_xor(na2, 2);
  nb2 += __shfl_xor(nb2, 1); nb2 += __shfl_xor(nb2, 2);

  if (q == 0) {
    float den = fmaxf(sqrtf(na2), 1e-8f) * fmaxf(sqrtf(nb2), 1e-8f);
    float ov  = d / den;
    float fid = ov * ov;
    out[blockIdx.x * 64 + p] = fminf(fid, 1.0f);
  }
}

extern "C" void kernel_launch(void* const* d_in, const int* in_sizes, int n_in,
                              void* d_out, int out_size, void* d_ws, size_t ws_size,
                              hipStream_t stream) {
  const float* img_a = (const float*)d_in[0];
  const float* img_b = (const float*)d_in[1];
  const float* W1    = (const float*)d_in[2];
  const float* b1    = (const float*)d_in[3];
  const float* W2    = (const float*)d_in[4];
  const float* b2    = (const float*)d_in[5];
  // d_in[6] = theta: unused — the circuit is unitary, fidelity is invariant.

  unsigned short* w1s = (unsigned short*)d_ws;
  float* w2t = (float*)((char*)d_ws + W1S_BYTES);

  prep_kernel<<<(W1S_ELEMS + 255) / 256, 256, 0, stream>>>(W1, W2, w1s, w2t);

  const int n_pairs = out_size;              // 65536
  qcm_kernel<<<n_pairs / 64, 256, 0, stream>>>(img_a, img_b, b1, b2, w1s, w2t,
                                               (float*)d_out);
}